// Round 4
// baseline (333.437 us; speedup 1.0000x reference)
//
#include <hip/hip_runtime.h>

// NeighborRoutingAgg: N=50000 nodes, M=32 neighbors, D=128 dims, 3 routing iters.
// Kernel A: invn[n] = 1/max(||x[n]||, eps)
// Kernel B: one wave per node; lane l owns dims (2l, 2l+1) as float2.
// x_nb dtype hedge: reference says int64, harness doc says int32. Valid ids are
// 1..N (never 0), so int64-as-int32 shows "odd words all 0, even words nonzero".
// Each wave probes the first 64 words (wave-uniform, grid-uniform branch).

#define M_NB 32
#define D_DIM 128
#define EPSN 1e-12f

__global__ __launch_bounds__(256) void invnorm_kernel(const float* __restrict__ x,
                                                      float* __restrict__ invn, int n) {
    int row  = (int)((blockIdx.x * blockDim.x + threadIdx.x) >> 6);
    int lane = threadIdx.x & 63;
    if (row >= n) return;
    float2 v = *reinterpret_cast<const float2*>(x + (size_t)row * D_DIM + 2 * lane);
    float s = v.x * v.x + v.y * v.y;
    #pragma unroll
    for (int off = 32; off; off >>= 1) s += __shfl_xor(s, off);
    if (lane == 0) invn[row] = 1.0f / fmaxf(sqrtf(s), EPSN);
}

__global__ __launch_bounds__(256) void routing_kernel(const float* __restrict__ x,
                                                      const int* __restrict__ nb,
                                                      const float* __restrict__ invn,
                                                      float* __restrict__ out, int n) {
    int node = (int)((blockIdx.x * blockDim.x + threadIdx.x) >> 6);
    int lane = threadIdx.x & 63;
    if (node >= n) return;

    // ---- dtype probe: int64 neighbor ids read as int32 words? ----
    int probe = nb[lane];
    bool sig  = (lane & 1) ? (probe == 0) : (probe != 0);
    bool is64 = __all(sig);

    // Load this node's 32 neighbor indices (1-indexed).
    size_t base = (size_t)node * M_NB + (lane & 31);
    int j = (is64 ? nb[2 * base] : nb[base]) - 1;
    float vinv = invn[j];

    // Gather normalized neighbor rows into registers: z[m] = xn[j_m][2l..2l+1]
    float2 z[M_NB];
    #pragma unroll
    for (int m = 0; m < M_NB; ++m) {
        int   jm = __shfl(j, m);
        float im = __shfl(vinv, m);
        float2 v = *reinterpret_cast<const float2*>(x + (size_t)jm * D_DIM + 2 * lane);
        z[m] = make_float2(v.x * im, v.y * im);
    }

    // Self normalized vector xn
    float2 xs = *reinterpret_cast<const float2*>(x + (size_t)node * D_DIM + 2 * lane);
    float  si = invn[node];
    float2 xn = make_float2(xs.x * si, xs.y * si);

    // ---- iteration 0: p = softmax(0) = 1/M, u = mean(z) + xn ----
    float2 u = make_float2(0.f, 0.f);
    #pragma unroll
    for (int m = 0; m < M_NB; ++m) { u.x += z[m].x; u.y += z[m].y; }
    u.x = u.x * (1.0f / M_NB) + xn.x;
    u.y = u.y * (1.0f / M_NB) + xn.y;

    // squash after it0
    {
        float sq = u.x * u.x + u.y * u.y;
        #pragma unroll
        for (int off = 32; off; off >>= 1) sq += __shfl_xor(sq, off);
        float scale = sq / ((sq + 1.0f) * fmaxf(sqrtf(sq), EPSN));
        u.x *= scale; u.y *= scale;
    }

    // ---- iterations 1 and 2 ----
    #pragma unroll
    for (int it = 1; it < 3; ++it) {
        // routing logits p[m] = z[m] . u   (wave-uniform after butterfly)
        float p[M_NB];
        #pragma unroll
        for (int m = 0; m < M_NB; ++m) {
            float t = z[m].x * u.x + z[m].y * u.y;
            #pragma unroll
            for (int off = 32; off; off >>= 1) t += __shfl_xor(t, off);
            p[m] = t;
        }
        // softmax over m (all values wave-uniform -> lane-local)
        float mx = p[0];
        #pragma unroll
        for (int m = 1; m < M_NB; ++m) mx = fmaxf(mx, p[m]);
        float sum = 0.f;
        #pragma unroll
        for (int m = 0; m < M_NB; ++m) { p[m] = __expf(p[m] - mx); sum += p[m]; }
        float rs = 1.0f / sum;

        // u = sum_m softmax(p)[m] * z[m] + xn
        float2 acc = make_float2(0.f, 0.f);
        #pragma unroll
        for (int m = 0; m < M_NB; ++m) { acc.x += p[m] * z[m].x; acc.y += p[m] * z[m].y; }
        u.x = acc.x * rs + xn.x;
        u.y = acc.y * rs + xn.y;

        if (it < 2) {  // squash except after final iteration
            float sq = u.x * u.x + u.y * u.y;
            #pragma unroll
            for (int off = 32; off; off >>= 1) sq += __shfl_xor(sq, off);
            float scale = sq / ((sq + 1.0f) * fmaxf(sqrtf(sq), EPSN));
            u.x *= scale; u.y *= scale;
        }
    }

    *reinterpret_cast<float2*>(out + (size_t)node * D_DIM + 2 * lane) = u;
}

extern "C" void kernel_launch(void* const* d_in, const int* in_sizes, int n_in,
                              void* d_out, int out_size, void* d_ws, size_t ws_size,
                              hipStream_t stream) {
    const float* x  = (const float*)d_in[0];
    const int*   nb = (const int*)d_in[1];
    float* out  = (float*)d_out;
    float* invn = (float*)d_ws;              // n floats of scratch

    int n = in_sizes[0] / D_DIM;             // 50000
    const int waves_per_block = 4;           // 256 threads
    int blocks = (n + waves_per_block - 1) / waves_per_block;

    invnorm_kernel<<<blocks, 256, 0, stream>>>(x, invn, n);
    routing_kernel<<<blocks, 256, 0, stream>>>(x, nb, invn, out, n);
}

// Round 6
// 163.185 us; speedup vs baseline: 2.0433x; 2.0433x over previous
//
#include <hip/hip_runtime.h>

// NeighborRoutingAgg: N=50000, M=32, D=128, 3 routing iters.
// Round 5 (resubmit): bf16 normalized-x table in d_ws (halves gather bytes +
// 128B granules, halves L2 footprint) + 4-rows-per-dwordx4 gather + 16-lane-group
// reductions (~140 cross-lane ops/wave vs ~460). Self xn kept f32-exact via invn.
// Fallback to the round-4 f32 path if ws_size < 13 MB.

#define M_NB 32
#define D_DIM 128
#define EPSN 1e-12f

// ---------- bf16-table path ----------

// Kernel A: xn table (bf16, RN-even) + invn. One wave per row.
__global__ __launch_bounds__(256) void prep_kernel(const float* __restrict__ x,
                                                   unsigned int* __restrict__ xnb,
                                                   float* __restrict__ invn, int n) {
    int row  = (int)((blockIdx.x * blockDim.x + threadIdx.x) >> 6);
    int lane = threadIdx.x & 63;
    if (row >= n) return;
    float2 v = *reinterpret_cast<const float2*>(x + (size_t)row * D_DIM + 2 * lane);
    float s = v.x * v.x + v.y * v.y;
    #pragma unroll
    for (int off = 32; off; off >>= 1) s += __shfl_xor(s, off);
    float inv = 1.0f / fmaxf(sqrtf(s), EPSN);
    if (lane == 0) invn[row] = inv;
    float a = v.x * inv, b = v.y * inv;
    unsigned int ba = __builtin_bit_cast(unsigned int, a);
    unsigned int bb = __builtin_bit_cast(unsigned int, b);
    unsigned int ra = (ba + 0x7fffu + ((ba >> 16) & 1u)) >> 16;          // low  16: dim 2l
    unsigned int rb = (bb + 0x7fffu + ((bb >> 16) & 1u)) & 0xffff0000u;  // high 16: dim 2l+1
    xnb[(size_t)row * 64 + lane] = ra | rb;
}

// Kernel B: one wave per node. g=lane>>4 (row group), t=lane&15 (dim slice 8t..8t+7).
__global__ __launch_bounds__(256) void routing_bf16_kernel(const float* __restrict__ x,
                                                           const int* __restrict__ nb,
                                                           const unsigned int* __restrict__ xnb,
                                                           const float* __restrict__ invn,
                                                           float* __restrict__ out, int n) {
    int node = (int)((blockIdx.x * blockDim.x + threadIdx.x) >> 6);
    int lane = threadIdx.x & 63;
    if (node >= n) return;
    int g = lane >> 4, t = lane & 15;

    // x_nb dtype probe (int64-as-int32: odd words all zero; ids are 1..N, never 0)
    int probe = nb[lane];
    bool sig  = (lane & 1) ? (probe == 0) : (probe != 0);
    bool is64 = __all(sig);

    size_t base = (size_t)node * M_NB + (lane & 31);
    int j = (is64 ? nb[2 * base] : nb[base]) - 1;

    // Gather: instruction i loads rows {4i+g}; lane reads 16B = dims 8t..8t+7 (bf16x8).
    uint4 zp[8];
    #pragma unroll
    for (int i = 0; i < 8; ++i) {
        int jm = __shfl(j, i * 4 + g);
        zp[i] = *reinterpret_cast<const uint4*>(xnb + (size_t)jm * 64 + t * 4);
    }

    // Self xn (f32-exact): dims 8t..8t+7
    float xn[8];
    {
        float4 a = *reinterpret_cast<const float4*>(x + (size_t)node * D_DIM + t * 8);
        float4 b = *reinterpret_cast<const float4*>(x + (size_t)node * D_DIM + t * 8 + 4);
        float inv = invn[node];
        xn[0] = a.x * inv; xn[1] = a.y * inv; xn[2] = a.z * inv; xn[3] = a.w * inv;
        xn[4] = b.x * inv; xn[5] = b.y * inv; xn[6] = b.z * inv; xn[7] = b.w * inv;
    }

    // Unpack bf16 -> f32 (dword c holds dims 2c [low], 2c+1 [high])
    float z[8][8];
    #pragma unroll
    for (int i = 0; i < 8; ++i) {
        unsigned int w0 = zp[i].x, w1 = zp[i].y, w2 = zp[i].z, w3 = zp[i].w;
        z[i][0] = __builtin_bit_cast(float, w0 << 16);
        z[i][1] = __builtin_bit_cast(float, w0 & 0xffff0000u);
        z[i][2] = __builtin_bit_cast(float, w1 << 16);
        z[i][3] = __builtin_bit_cast(float, w1 & 0xffff0000u);
        z[i][4] = __builtin_bit_cast(float, w2 << 16);
        z[i][5] = __builtin_bit_cast(float, w2 & 0xffff0000u);
        z[i][6] = __builtin_bit_cast(float, w3 << 16);
        z[i][7] = __builtin_bit_cast(float, w3 & 0xffff0000u);
    }

    // ---- it0: u = mean_m(z) + xn. Cross-group reduce (xor16, xor32) -> replicated.
    float u[8];
    #pragma unroll
    for (int e = 0; e < 8; ++e) {
        float s = 0.f;
        #pragma unroll
        for (int i = 0; i < 8; ++i) s += z[i][e];
        s += __shfl_xor(s, 16);
        s += __shfl_xor(s, 32);
        u[e] = s * (1.0f / M_NB) + xn[e];
    }
    // squash (reduce over t: xor 1,2,4,8 covers all 128 dims within a group)
    {
        float sq = 0.f;
        #pragma unroll
        for (int e = 0; e < 8; ++e) sq += u[e] * u[e];
        #pragma unroll
        for (int off = 1; off <= 8; off <<= 1) sq += __shfl_xor(sq, off);
        float scale = sq / ((sq + 1.0f) * fmaxf(sqrtf(sq), EPSN));
        #pragma unroll
        for (int e = 0; e < 8; ++e) u[e] *= scale;
    }

    // ---- iterations 1, 2 ----
    #pragma unroll
    for (int it = 1; it < 3; ++it) {
        // dots: p[i] = z[4i+g] . u  (reduce over t)
        float p[8];
        #pragma unroll
        for (int i = 0; i < 8; ++i) {
            float pd = 0.f;
            #pragma unroll
            for (int e = 0; e < 8; ++e) pd += z[i][e] * u[e];
            #pragma unroll
            for (int off = 1; off <= 8; off <<= 1) pd += __shfl_xor(pd, off);
            p[i] = pd;
        }
        // softmax over 32 rows: 8 local x 4 groups
        float mx = p[0];
        #pragma unroll
        for (int i = 1; i < 8; ++i) mx = fmaxf(mx, p[i]);
        mx = fmaxf(mx, __shfl_xor(mx, 16));
        mx = fmaxf(mx, __shfl_xor(mx, 32));
        float sum = 0.f;
        #pragma unroll
        for (int i = 0; i < 8; ++i) { p[i] = __expf(p[i] - mx); sum += p[i]; }
        sum += __shfl_xor(sum, 16);
        sum += __shfl_xor(sum, 32);
        float rs = 1.0f / sum;
        // weighted sum + cross-group reduce
        #pragma unroll
        for (int e = 0; e < 8; ++e) {
            float a = 0.f;
            #pragma unroll
            for (int i = 0; i < 8; ++i) a += p[i] * z[i][e];
            a += __shfl_xor(a, 16);
            a += __shfl_xor(a, 32);
            u[e] = a * rs + xn[e];
        }
        if (it < 2) {
            float sq = 0.f;
            #pragma unroll
            for (int e = 0; e < 8; ++e) sq += u[e] * u[e];
            #pragma unroll
            for (int off = 1; off <= 8; off <<= 1) sq += __shfl_xor(sq, off);
            float scale = sq / ((sq + 1.0f) * fmaxf(sqrtf(sq), EPSN));
            #pragma unroll
            for (int e = 0; e < 8; ++e) u[e] *= scale;
        }
    }

    // write: groups 0/1 emit 32 lanes x 16B = full 512B row (static indices only)
    if (g == 0) {
        *reinterpret_cast<float4*>(out + (size_t)node * D_DIM + t * 8) =
            make_float4(u[0], u[1], u[2], u[3]);
    } else if (g == 1) {
        *reinterpret_cast<float4*>(out + (size_t)node * D_DIM + t * 8 + 4) =
            make_float4(u[4], u[5], u[6], u[7]);
    }
}

// ---------- fallback f32 path (round-4, proven) ----------

__global__ __launch_bounds__(256) void invnorm_kernel(const float* __restrict__ x,
                                                      float* __restrict__ invn, int n) {
    int row  = (int)((blockIdx.x * blockDim.x + threadIdx.x) >> 6);
    int lane = threadIdx.x & 63;
    if (row >= n) return;
    float2 v = *reinterpret_cast<const float2*>(x + (size_t)row * D_DIM + 2 * lane);
    float s = v.x * v.x + v.y * v.y;
    #pragma unroll
    for (int off = 32; off; off >>= 1) s += __shfl_xor(s, off);
    if (lane == 0) invn[row] = 1.0f / fmaxf(sqrtf(s), EPSN);
}

__global__ __launch_bounds__(256) void routing_kernel(const float* __restrict__ x,
                                                      const int* __restrict__ nb,
                                                      const float* __restrict__ invn,
                                                      float* __restrict__ out, int n) {
    int node = (int)((blockIdx.x * blockDim.x + threadIdx.x) >> 6);
    int lane = threadIdx.x & 63;
    if (node >= n) return;

    int probe = nb[lane];
    bool sig  = (lane & 1) ? (probe == 0) : (probe != 0);
    bool is64 = __all(sig);

    size_t base = (size_t)node * M_NB + (lane & 31);
    int j = (is64 ? nb[2 * base] : nb[base]) - 1;
    float vinv = invn[j];

    float2 z[M_NB];
    #pragma unroll
    for (int m = 0; m < M_NB; ++m) {
        int   jm = __shfl(j, m);
        float im = __shfl(vinv, m);
        float2 v = *reinterpret_cast<const float2*>(x + (size_t)jm * D_DIM + 2 * lane);
        z[m] = make_float2(v.x * im, v.y * im);
    }

    float2 xs = *reinterpret_cast<const float2*>(x + (size_t)node * D_DIM + 2 * lane);
    float  si = invn[node];
    float2 xn = make_float2(xs.x * si, xs.y * si);

    float2 u = make_float2(0.f, 0.f);
    #pragma unroll
    for (int m = 0; m < M_NB; ++m) { u.x += z[m].x; u.y += z[m].y; }
    u.x = u.x * (1.0f / M_NB) + xn.x;
    u.y = u.y * (1.0f / M_NB) + xn.y;
    {
        float sq = u.x * u.x + u.y * u.y;
        #pragma unroll
        for (int off = 32; off; off >>= 1) sq += __shfl_xor(sq, off);
        float scale = sq / ((sq + 1.0f) * fmaxf(sqrtf(sq), EPSN));
        u.x *= scale; u.y *= scale;
    }
    #pragma unroll
    for (int it = 1; it < 3; ++it) {
        float p[M_NB];
        #pragma unroll
        for (int m = 0; m < M_NB; ++m) {
            float tt = z[m].x * u.x + z[m].y * u.y;
            #pragma unroll
            for (int off = 32; off; off >>= 1) tt += __shfl_xor(tt, off);
            p[m] = tt;
        }
        float mx = p[0];
        #pragma unroll
        for (int m = 1; m < M_NB; ++m) mx = fmaxf(mx, p[m]);
        float sum = 0.f;
        #pragma unroll
        for (int m = 0; m < M_NB; ++m) { p[m] = __expf(p[m] - mx); sum += p[m]; }
        float rs = 1.0f / sum;
        float2 acc = make_float2(0.f, 0.f);
        #pragma unroll
        for (int m = 0; m < M_NB; ++m) { acc.x += p[m] * z[m].x; acc.y += p[m] * z[m].y; }
        u.x = acc.x * rs + xn.x;
        u.y = acc.y * rs + xn.y;
        if (it < 2) {
            float sq = u.x * u.x + u.y * u.y;
            #pragma unroll
            for (int off = 32; off; off >>= 1) sq += __shfl_xor(sq, off);
            float scale = sq / ((sq + 1.0f) * fmaxf(sqrtf(sq), EPSN));
            u.x *= scale; u.y *= scale;
        }
    }
    *reinterpret_cast<float2*>(out + (size_t)node * D_DIM + 2 * lane) = u;
}

extern "C" void kernel_launch(void* const* d_in, const int* in_sizes, int n_in,
                              void* d_out, int out_size, void* d_ws, size_t ws_size,
                              hipStream_t stream) {
    const float* x  = (const float*)d_in[0];
    const int*   nb = (const int*)d_in[1];
    float* out = (float*)d_out;

    int n = in_sizes[0] / D_DIM;  // 50000
    int blocks = (n + 3) / 4;     // 4 waves (nodes/rows) per 256-thread block

    size_t xnb_bytes = (size_t)n * D_DIM * 2;  // 12.8 MB
    size_t need = xnb_bytes + (size_t)n * 4;   // + invn

    if (ws_size >= need) {
        unsigned int* xnb = (unsigned int*)d_ws;
        float* invn = (float*)((char*)d_ws + xnb_bytes);
        prep_kernel<<<blocks, 256, 0, stream>>>(x, xnb, invn, n);
        routing_bf16_kernel<<<blocks, 256, 0, stream>>>(x, nb, xnb, invn, out, n);
    } else {
        float* invn = (float*)d_ws;
        invnorm_kernel<<<blocks, 256, 0, stream>>>(x, invn, n);
        routing_kernel<<<blocks, 256, 0, stream>>>(x, nb, invn, out, n);
    }
}

// Round 7
// 159.398 us; speedup vs baseline: 2.0919x; 1.0238x over previous
//
#include <hip/hip_runtime.h>

// NeighborRoutingAgg: N=50000, M=32, D=128, 3 routing iters.
// Round 7: r6 showed VALU-bound (68% busy) with VGPR=56 -> compiler kept z
// PACKED and re-unpacked bf16->f32 at every use (~500+ remat VALU ops/wave).
// Fix: __launch_bounds__(256,4) caps at 4 waves/SIMD (VGPR<=128) so unpacked
// z[8][4] float2 stays resident; all inner math in float2 pairs to trigger
// v_pk_fma_f32 (double-rate packed f32). Structure otherwise identical to the
// verified r6 kernel. Fallback f32 path retained.

#define M_NB 32
#define D_DIM 128
#define EPSN 1e-12f

__device__ __forceinline__ float2 f2(float a, float b) { return make_float2(a, b); }

// ---------- bf16-table path ----------

// Kernel A: xn table (bf16, RN-even) + invn. One wave per row.
__global__ __launch_bounds__(256) void prep_kernel(const float* __restrict__ x,
                                                   unsigned int* __restrict__ xnb,
                                                   float* __restrict__ invn, int n) {
    int row  = (int)((blockIdx.x * blockDim.x + threadIdx.x) >> 6);
    int lane = threadIdx.x & 63;
    if (row >= n) return;
    float2 v = *reinterpret_cast<const float2*>(x + (size_t)row * D_DIM + 2 * lane);
    float s = v.x * v.x + v.y * v.y;
    #pragma unroll
    for (int off = 32; off; off >>= 1) s += __shfl_xor(s, off);
    float inv = 1.0f / fmaxf(sqrtf(s), EPSN);
    if (lane == 0) invn[row] = inv;
    float a = v.x * inv, b = v.y * inv;
    unsigned int ba = __builtin_bit_cast(unsigned int, a);
    unsigned int bb = __builtin_bit_cast(unsigned int, b);
    unsigned int ra = (ba + 0x7fffu + ((ba >> 16) & 1u)) >> 16;          // low  16: dim 2l
    unsigned int rb = (bb + 0x7fffu + ((bb >> 16) & 1u)) & 0xffff0000u;  // high 16: dim 2l+1
    xnb[(size_t)row * 64 + lane] = ra | rb;
}

// Kernel B: one wave per node. g=lane>>4 (row group), t=lane&15 (dim slice 8t..8t+7).
// launch_bounds(256,4): 4 waves/EU -> VGPR cap 128, keeps z resident.
__global__ __launch_bounds__(256, 4) void routing_bf16_kernel(const float* __restrict__ x,
                                                              const int* __restrict__ nb,
                                                              const unsigned int* __restrict__ xnb,
                                                              const float* __restrict__ invn,
                                                              float* __restrict__ out, int n) {
    int node = (int)((blockIdx.x * blockDim.x + threadIdx.x) >> 6);
    int lane = threadIdx.x & 63;
    if (node >= n) return;
    int g = lane >> 4, t = lane & 15;

    // x_nb dtype probe (int64-as-int32: odd words all zero; ids are 1..N, never 0)
    int probe = nb[lane];
    bool sig  = (lane & 1) ? (probe == 0) : (probe != 0);
    bool is64 = __all(sig);

    size_t base = (size_t)node * M_NB + (lane & 31);
    int j = (is64 ? nb[2 * base] : nb[base]) - 1;

    // Gather: instruction i loads row 4i+g; lane reads 16B = dims 8t..8t+7 (bf16x8).
    uint4 zp[8];
    #pragma unroll
    for (int i = 0; i < 8; ++i) {
        int jm = __shfl(j, i * 4 + g);
        zp[i] = *reinterpret_cast<const uint4*>(xnb + (size_t)jm * 64 + t * 4);
    }

    // Self xn (f32-exact): dims 8t..8t+7, as 4 float2 pairs
    float2 xn2[4];
    {
        float4 a = *reinterpret_cast<const float4*>(x + (size_t)node * D_DIM + t * 8);
        float4 b = *reinterpret_cast<const float4*>(x + (size_t)node * D_DIM + t * 8 + 4);
        float inv = invn[node];
        xn2[0] = f2(a.x * inv, a.y * inv);
        xn2[1] = f2(a.z * inv, a.w * inv);
        xn2[2] = f2(b.x * inv, b.y * inv);
        xn2[3] = f2(b.z * inv, b.w * inv);
    }

    // Unpack bf16 -> f32 ONCE; z2[i][c] = dims (8t+2c, 8t+2c+1) of row 4i+g.
    float2 z2[8][4];
    #pragma unroll
    for (int i = 0; i < 8; ++i) {
        unsigned int w[4] = { zp[i].x, zp[i].y, zp[i].z, zp[i].w };
        #pragma unroll
        for (int c = 0; c < 4; ++c) {
            z2[i][c] = f2(__builtin_bit_cast(float, w[c] << 16),
                          __builtin_bit_cast(float, w[c] & 0xffff0000u));
        }
    }

    // ---- it0: u = mean_m(z) + xn (cross-group reduce xor16, xor32) ----
    float2 u2[4];
    #pragma unroll
    for (int c = 0; c < 4; ++c) {
        float2 s = f2(0.f, 0.f);
        #pragma unroll
        for (int i = 0; i < 8; ++i) { s.x += z2[i][c].x; s.y += z2[i][c].y; }
        s.x += __shfl_xor(s.x, 16);  s.y += __shfl_xor(s.y, 16);
        s.x += __shfl_xor(s.x, 32);  s.y += __shfl_xor(s.y, 32);
        u2[c] = f2(s.x * (1.0f / M_NB) + xn2[c].x, s.y * (1.0f / M_NB) + xn2[c].y);
    }
    // squash (reduce over t: xor 1,2,4,8)
    {
        float sq = 0.f;
        #pragma unroll
        for (int c = 0; c < 4; ++c) sq += u2[c].x * u2[c].x + u2[c].y * u2[c].y;
        #pragma unroll
        for (int off = 1; off <= 8; off <<= 1) sq += __shfl_xor(sq, off);
        float scale = sq / ((sq + 1.0f) * fmaxf(sqrtf(sq), EPSN));
        #pragma unroll
        for (int c = 0; c < 4; ++c) { u2[c].x *= scale; u2[c].y *= scale; }
    }

    // ---- iterations 1, 2 ----
    #pragma unroll
    for (int it = 1; it < 3; ++it) {
        // dots: p[i] = z[4i+g] . u (pairwise fma then 16-lane reduce)
        float p[8];
        #pragma unroll
        for (int i = 0; i < 8; ++i) {
            float2 a = f2(0.f, 0.f);
            #pragma unroll
            for (int c = 0; c < 4; ++c) {
                a.x += z2[i][c].x * u2[c].x;
                a.y += z2[i][c].y * u2[c].y;
            }
            float pd = a.x + a.y;
            #pragma unroll
            for (int off = 1; off <= 8; off <<= 1) pd += __shfl_xor(pd, off);
            p[i] = pd;
        }
        // softmax over 32 rows: 8 local x 4 groups
        float mx = p[0];
        #pragma unroll
        for (int i = 1; i < 8; ++i) mx = fmaxf(mx, p[i]);
        mx = fmaxf(mx, __shfl_xor(mx, 16));
        mx = fmaxf(mx, __shfl_xor(mx, 32));
        float sum = 0.f;
        #pragma unroll
        for (int i = 0; i < 8; ++i) { p[i] = __expf(p[i] - mx); sum += p[i]; }
        sum += __shfl_xor(sum, 16);
        sum += __shfl_xor(sum, 32);
        float rs = 1.0f / sum;
        // weighted sum + cross-group reduce
        #pragma unroll
        for (int c = 0; c < 4; ++c) {
            float2 a = f2(0.f, 0.f);
            #pragma unroll
            for (int i = 0; i < 8; ++i) {
                a.x += p[i] * z2[i][c].x;
                a.y += p[i] * z2[i][c].y;
            }
            a.x += __shfl_xor(a.x, 16);  a.y += __shfl_xor(a.y, 16);
            a.x += __shfl_xor(a.x, 32);  a.y += __shfl_xor(a.y, 32);
            u2[c] = f2(a.x * rs + xn2[c].x, a.y * rs + xn2[c].y);
        }
        if (it < 2) {
            float sq = 0.f;
            #pragma unroll
            for (int c = 0; c < 4; ++c) sq += u2[c].x * u2[c].x + u2[c].y * u2[c].y;
            #pragma unroll
            for (int off = 1; off <= 8; off <<= 1) sq += __shfl_xor(sq, off);
            float scale = sq / ((sq + 1.0f) * fmaxf(sqrtf(sq), EPSN));
            #pragma unroll
            for (int c = 0; c < 4; ++c) { u2[c].x *= scale; u2[c].y *= scale; }
        }
    }

    // write: groups 0/1 emit 32 lanes x 16B = full 512B row (static indices only)
    if (g == 0) {
        *reinterpret_cast<float4*>(out + (size_t)node * D_DIM + t * 8) =
            make_float4(u2[0].x, u2[0].y, u2[1].x, u2[1].y);
    } else if (g == 1) {
        *reinterpret_cast<float4*>(out + (size_t)node * D_DIM + t * 8 + 4) =
            make_float4(u2[2].x, u2[2].y, u2[3].x, u2[3].y);
    }
}

// ---------- fallback f32 path (round-4, proven) ----------

__global__ __launch_bounds__(256) void invnorm_kernel(const float* __restrict__ x,
                                                      float* __restrict__ invn, int n) {
    int row  = (int)((blockIdx.x * blockDim.x + threadIdx.x) >> 6);
    int lane = threadIdx.x & 63;
    if (row >= n) return;
    float2 v = *reinterpret_cast<const float2*>(x + (size_t)row * D_DIM + 2 * lane);
    float s = v.x * v.x + v.y * v.y;
    #pragma unroll
    for (int off = 32; off; off >>= 1) s += __shfl_xor(s, off);
    if (lane == 0) invn[row] = 1.0f / fmaxf(sqrtf(s), EPSN);
}

__global__ __launch_bounds__(256) void routing_kernel(const float* __restrict__ x,
                                                      const int* __restrict__ nb,
                                                      const float* __restrict__ invn,
                                                      float* __restrict__ out, int n) {
    int node = (int)((blockIdx.x * blockDim.x + threadIdx.x) >> 6);
    int lane = threadIdx.x & 63;
    if (node >= n) return;

    int probe = nb[lane];
    bool sig  = (lane & 1) ? (probe == 0) : (probe != 0);
    bool is64 = __all(sig);

    size_t base = (size_t)node * M_NB + (lane & 31);
    int j = (is64 ? nb[2 * base] : nb[base]) - 1;
    float vinv = invn[j];

    float2 z[M_NB];
    #pragma unroll
    for (int m = 0; m < M_NB; ++m) {
        int   jm = __shfl(j, m);
        float im = __shfl(vinv, m);
        float2 v = *reinterpret_cast<const float2*>(x + (size_t)jm * D_DIM + 2 * lane);
        z[m] = make_float2(v.x * im, v.y * im);
    }

    float2 xs = *reinterpret_cast<const float2*>(x + (size_t)node * D_DIM + 2 * lane);
    float  si = invn[node];
    float2 xn = make_float2(xs.x * si, xs.y * si);

    float2 u = make_float2(0.f, 0.f);
    #pragma unroll
    for (int m = 0; m < M_NB; ++m) { u.x += z[m].x; u.y += z[m].y; }
    u.x = u.x * (1.0f / M_NB) + xn.x;
    u.y = u.y * (1.0f / M_NB) + xn.y;
    {
        float sq = u.x * u.x + u.y * u.y;
        #pragma unroll
        for (int off = 32; off; off >>= 1) sq += __shfl_xor(sq, off);
        float scale = sq / ((sq + 1.0f) * fmaxf(sqrtf(sq), EPSN));
        u.x *= scale; u.y *= scale;
    }
    #pragma unroll
    for (int it = 1; it < 3; ++it) {
        float p[M_NB];
        #pragma unroll
        for (int m = 0; m < M_NB; ++m) {
            float tt = z[m].x * u.x + z[m].y * u.y;
            #pragma unroll
            for (int off = 32; off; off >>= 1) tt += __shfl_xor(tt, off);
            p[m] = tt;
        }
        float mx = p[0];
        #pragma unroll
        for (int m = 1; m < M_NB; ++m) mx = fmaxf(mx, p[m]);
        float sum = 0.f;
        #pragma unroll
        for (int m = 0; m < M_NB; ++m) { p[m] = __expf(p[m] - mx); sum += p[m]; }
        float rs = 1.0f / sum;
        float2 acc = make_float2(0.f, 0.f);
        #pragma unroll
        for (int m = 0; m < M_NB; ++m) { acc.x += p[m] * z[m].x; acc.y += p[m] * z[m].y; }
        u.x = acc.x * rs + xn.x;
        u.y = acc.y * rs + xn.y;
        if (it < 2) {
            float sq = u.x * u.x + u.y * u.y;
            #pragma unroll
            for (int off = 32; off; off >>= 1) sq += __shfl_xor(sq, off);
            float scale = sq / ((sq + 1.0f) * fmaxf(sqrtf(sq), EPSN));
            u.x *= scale; u.y *= scale;
        }
    }
    *reinterpret_cast<float2*>(out + (size_t)node * D_DIM + 2 * lane) = u;
}

extern "C" void kernel_launch(void* const* d_in, const int* in_sizes, int n_in,
                              void* d_out, int out_size, void* d_ws, size_t ws_size,
                              hipStream_t stream) {
    const float* x  = (const float*)d_in[0];
    const int*   nb = (const int*)d_in[1];
    float* out = (float*)d_out;

    int n = in_sizes[0] / D_DIM;  // 50000
    int blocks = (n + 3) / 4;     // 4 waves (nodes/rows) per 256-thread block

    size_t xnb_bytes = (size_t)n * D_DIM * 2;  // 12.8 MB
    size_t need = xnb_bytes + (size_t)n * 4;   // + invn

    if (ws_size >= need) {
        unsigned int* xnb = (unsigned int*)d_ws;
        float* invn = (float*)((char*)d_ws + xnb_bytes);
        prep_kernel<<<blocks, 256, 0, stream>>>(x, xnb, invn, n);
        routing_bf16_kernel<<<blocks, 256, 0, stream>>>(x, nb, xnb, invn, out, n);
    } else {
        float* invn = (float*)d_ws;
        invnorm_kernel<<<blocks, 256, 0, stream>>>(x, invn, n);
        routing_kernel<<<blocks, 256, 0, stream>>>(x, nb, invn, out, n);
    }
}